// Round 2
// baseline (40.412 us; speedup 1.0000x reference)
//
#include <hip/hip_runtime.h>
#include <stdint.h>

// BLS12-377 Fr: p = 0x12ab655e9a2ca55660b44d1e5c37b00159aa76fed00000010a11800000000001
//
// Reference computes (a*R mod p + b*R mod p) mod p, canonical in [0,p), R = 2^256.
// Inputs a,b have 4 limbs each < 2^31 (values < 2^223), so a+b < 2^224 < p and the
// result equals (a+b)*R mod p. With s_k = a_k + b_k (< 2^32, no carries, k=0..3 at
// 64-bit limb positions), result = (sum_k s_k * D_k) * 2^-128 mod p where
// D_k = 2^(384+64k) mod p. 4 CIOS mul rows + 4 REDC steps + 1 cond_sub -> canonical,
// bit-exact vs reference.
//
// Harness passes integer tensors as int32: d_in[i] = int32[N*4] (limbs < 2^31),
// d_out = int32[N*4] = low 32 bits of each 64-bit output word = even 32-bit limbs.

#define MASK32 0xffffffffull

namespace {

constexpr uint32_t PL[8] = {
  0x00000001u, 0x0a118000u, 0xd0000001u, 0x59aa76feu,
  0x5c37b001u, 0x60b44d1eu, 0x9a2ca556u, 0x12ab655eu
};

struct U256 { uint32_t l[8]; };

constexpr bool geq_p(const U256& x) {
  for (int i = 7; i >= 0; --i) {
    if (x.l[i] != PL[i]) return x.l[i] > PL[i];
  }
  return true;  // equal
}

// 2^e mod p via double-and-reduce from 2^252 (< p since p > 2^252).
constexpr U256 pow2_mod(int e) {
  U256 x{};
  for (int i = 0; i < 8; ++i) x.l[i] = 0;
  x.l[7] = 0x10000000u;  // 2^252
  for (int it = 0; it < e - 252; ++it) {
    uint32_t carry = 0;
    for (int j = 0; j < 8; ++j) {
      uint32_t nc = x.l[j] >> 31;
      x.l[j] = (x.l[j] << 1) | carry;
      carry = nc;
    }
    if (geq_p(x)) {
      uint64_t borrow = 0;
      for (int j = 0; j < 8; ++j) {
        uint64_t d = (uint64_t)x.l[j] - (uint64_t)PL[j] - borrow;
        x.l[j] = (uint32_t)d;
        borrow = (d >> 32) & 1ull;
      }
    }
  }
  return x;
}

constexpr U256 D0 = pow2_mod(384);
constexpr U256 D1 = pow2_mod(448);
constexpr U256 D2 = pow2_mod(512);
constexpr U256 D3 = pow2_mod(576);

}  // namespace

__global__ __launch_bounds__(256) void fr_tomont_add_kernel(
    const int4* __restrict__ in1,
    const int4* __restrict__ in2,
    int4* __restrict__ out,
    int n) {
  int idx = blockIdx.x * blockDim.x + threadIdx.x;
  if (idx >= n) return;

  int4 av = in1[idx];
  int4 bv = in2[idx];

  // s_k = a_k + b_k, each input limb < 2^31 so sum < 2^32 (no 64-bit-limb carries)
  uint64_t s0 = (uint64_t)(uint32_t)av.x + (uint64_t)(uint32_t)bv.x;
  uint64_t s1 = (uint64_t)(uint32_t)av.y + (uint64_t)(uint32_t)bv.y;
  uint64_t s2 = (uint64_t)(uint32_t)av.z + (uint64_t)(uint32_t)bv.z;
  uint64_t s3 = (uint64_t)(uint32_t)av.w + (uint64_t)(uint32_t)bv.w;

  // T = s0*D0 + s1*D1 + s2*D2 + s3*D3   (T < 2^34 * p < 2^287, 9 limbs)
  uint64_t t[9];
#pragma unroll
  for (int j = 0; j < 9; ++j) t[j] = 0;

  const uint32_t* Dk[4] = {D0.l, D1.l, D2.l, D3.l};
  const uint64_t sk[4] = {s0, s1, s2, s3};
#pragma unroll
  for (int k = 0; k < 4; ++k) {
    uint64_t c = 0;
#pragma unroll
    for (int j = 0; j < 8; ++j) {
      uint64_t m = t[j] + sk[k] * (uint64_t)Dk[k][j] + c;  // < 2^64, no overflow
      t[j] = m & MASK32;
      c = m >> 32;
    }
    t[8] += c;
  }

  // 4 Montgomery REDC steps: T <- (T + m*p)/2^32, m = -T mod 2^32 (p[0]==1).
  // After 4 steps: T == original * 2^-128 mod p, T < 2p.
#pragma unroll
  for (int step = 0; step < 4; ++step) {
    uint32_t m = (uint32_t)0u - (uint32_t)t[0];
    uint64_t c = (t[0] != 0) ? 1ull : 0ull;  // t[0] + m*1 == 0 or 2^32
#pragma unroll
    for (int j = 1; j < 8; ++j) {
      uint64_t x = t[j] + (uint64_t)m * (uint64_t)PL[j] + c;
      t[j - 1] = x & MASK32;
      c = x >> 32;
    }
    uint64_t x = t[8] + c;
    t[7] = x & MASK32;
    t[8] = x >> 32;
  }

  // cond_sub: subtract p once if t >= p (or extra word nonzero) -> canonical
  uint32_t d[8];
  uint64_t borrow = 0;
#pragma unroll
  for (int j = 0; j < 8; ++j) {
    uint64_t x = t[j] - (uint64_t)PL[j] - borrow;
    d[j] = (uint32_t)x;
    borrow = (x >> 32) & 1ull;
  }
  bool use = (t[8] != 0) || (borrow == 0);
  uint32_t r0 = use ? d[0] : (uint32_t)t[0];
  uint32_t r2 = use ? d[2] : (uint32_t)t[2];
  uint32_t r4 = use ? d[4] : (uint32_t)t[4];
  uint32_t r6 = use ? d[6] : (uint32_t)t[6];

  // Output int32 = low 32 bits of each 64-bit word = even 32-bit limbs.
  out[idx] = make_int4((int)r0, (int)r2, (int)r4, (int)r6);
}

extern "C" void kernel_launch(void* const* d_in, const int* in_sizes, int n_in,
                              void* d_out, int out_size, void* d_ws, size_t ws_size,
                              hipStream_t stream) {
  const int4* in1 = (const int4*)d_in[0];
  const int4* in2 = (const int4*)d_in[1];
  int4* out = (int4*)d_out;
  int n = in_sizes[0] / 4;  // (N,4) -> N elements

  const int block = 256;
  const int grid = (n + block - 1) / block;
  fr_tomont_add_kernel<<<grid, block, 0, stream>>>(in1, in2, out, n);
}

// Round 3
// 35.434 us; speedup vs baseline: 1.1405x; 1.1405x over previous
//
#include <hip/hip_runtime.h>
#include <stdint.h>

// BLS12-377 Fr: p = 0x12ab655e9a2ca55660b44d1e5c37b00159aa76fed00000010a11800000000001
//
// Reference computes (a*R mod p + b*R mod p) mod p, canonical in [0,p), R = 2^256.
// Inputs a,b each have 4 64-bit limbs < 2^31 (values < 2^223), so a+b < 2^224 < p and
// the result equals (a+b)*R mod p. With s_k = a_k + b_k (< 2^32, no inter-limb carry),
// result = (sum_k s_k * D_k) * 2^-64 mod p where D_k = 2^(320+64k) mod p.
//
// Bounds: T0 = sum s_k*D_k < 2^34*p (9 limbs, top limb < 2^31).
//   REDC step 1: T1 < 5p < 2^255  (top word vanishes -> 8 limbs)
//   REDC step 2: T2 < 2p          (single cond_sub -> canonical, bit-exact vs ref)
//
// Harness dtypes: inputs int32[N*4] (limbs < 2^31), output int32[N*4] = low 32 bits
// of each 64-bit output word = even 32-bit limbs of the canonical residue.

#define MASK32 0xffffffffull

namespace {

constexpr uint32_t PL[8] = {
  0x00000001u, 0x0a118000u, 0xd0000001u, 0x59aa76feu,
  0x5c37b001u, 0x60b44d1eu, 0x9a2ca556u, 0x12ab655eu
};

struct U256 { uint32_t l[8]; };

constexpr bool geq_p(const U256& x) {
  for (int i = 7; i >= 0; --i) {
    if (x.l[i] != PL[i]) return x.l[i] > PL[i];
  }
  return true;  // equal
}

// 2^e mod p via double-and-reduce from 2^252 (< p since p > 2^252).
constexpr U256 pow2_mod(int e) {
  U256 x{};
  for (int i = 0; i < 8; ++i) x.l[i] = 0;
  x.l[7] = 0x10000000u;  // 2^252
  for (int it = 0; it < e - 252; ++it) {
    uint32_t carry = 0;
    for (int j = 0; j < 8; ++j) {
      uint32_t nc = x.l[j] >> 31;
      x.l[j] = (x.l[j] << 1) | carry;
      carry = nc;
    }
    if (geq_p(x)) {
      uint64_t borrow = 0;
      for (int j = 0; j < 8; ++j) {
        uint64_t d = (uint64_t)x.l[j] - (uint64_t)PL[j] - borrow;
        x.l[j] = (uint32_t)d;
        borrow = (d >> 32) & 1ull;
      }
    }
  }
  return x;
}

constexpr U256 D0 = pow2_mod(320);
constexpr U256 D1 = pow2_mod(384);
constexpr U256 D2 = pow2_mod(448);
constexpr U256 D3 = pow2_mod(512);

}  // namespace

__global__ __launch_bounds__(256) void fr_tomont_add_kernel(
    const int4* __restrict__ in1,
    const int4* __restrict__ in2,
    int4* __restrict__ out,
    int n) {
  int idx = blockIdx.x * blockDim.x + threadIdx.x;
  if (idx >= n) return;

  int4 av = in1[idx];
  int4 bv = in2[idx];

  // s_k = a_k + b_k, each input limb < 2^31 so the 32-bit sum cannot overflow
  uint32_t s0 = (uint32_t)av.x + (uint32_t)bv.x;
  uint32_t s1 = (uint32_t)av.y + (uint32_t)bv.y;
  uint32_t s2 = (uint32_t)av.z + (uint32_t)bv.z;
  uint32_t s3 = (uint32_t)av.w + (uint32_t)bv.w;

  uint64_t t[9];

  // Row 0: t = s0 * D0  (no accumulate)
  {
    uint64_t c = 0;
#pragma unroll
    for (int j = 0; j < 8; ++j) {
      uint64_t x = (uint64_t)s0 * (uint64_t)D0.l[j] + c;
      t[j] = x & MASK32;
      c = x >> 32;
    }
    t[8] = c;
  }

  // Rows 1..3: t += s_k * D_k
  {
    const uint32_t* Dk[3] = {D1.l, D2.l, D3.l};
    const uint32_t sk[3] = {s1, s2, s3};
#pragma unroll
    for (int k = 0; k < 3; ++k) {
      uint64_t c = 0;
#pragma unroll
      for (int j = 0; j < 8; ++j) {
        uint64_t x = t[j] + (uint64_t)sk[k] * (uint64_t)Dk[k][j] + c;
        t[j] = x & MASK32;
        c = x >> 32;
      }
      t[8] += c;  // t[8] < 2^31 (T0 < 2^287)
    }
  }

  // REDC step 1 (9 limbs -> 8): m = -t0 mod 2^32 (p[0] == 1)
  {
    uint32_t m = (uint32_t)0u - (uint32_t)t[0];
    uint64_t c = ((uint32_t)t[0] != 0u) ? 1ull : 0ull;  // carry of t0 + m*1
#pragma unroll
    for (int j = 1; j < 8; ++j) {
      uint64_t x = t[j] + (uint64_t)m * (uint64_t)PL[j] + c;
      t[j - 1] = x & MASK32;
      c = x >> 32;
    }
    // T1 < 5p < 2^255 -> top limb < 2^31, no overflow word
    t[7] = t[8] + c;
  }

  // REDC step 2 (8 limbs): T2 < 2p
  {
    uint32_t m = (uint32_t)0u - (uint32_t)t[0];
    uint64_t c = ((uint32_t)t[0] != 0u) ? 1ull : 0ull;
#pragma unroll
    for (int j = 1; j < 8; ++j) {
      uint64_t x = t[j] + (uint64_t)m * (uint64_t)PL[j] + c;
      t[j - 1] = x & MASK32;
      c = x >> 32;
    }
    t[7] = c;  // < 2^32
  }

  // cond_sub: T2 < 2p, subtract p iff t >= p (no borrow) -> canonical residue
  uint32_t d[8];
  uint64_t borrow = 0;
#pragma unroll
  for (int j = 0; j < 8; ++j) {
    uint64_t x = t[j] - (uint64_t)PL[j] - borrow;
    d[j] = (uint32_t)x;
    borrow = (x >> 32) & 1ull;
  }
  bool use = (borrow == 0);
  uint32_t r0 = use ? d[0] : (uint32_t)t[0];
  uint32_t r2 = use ? d[2] : (uint32_t)t[2];
  uint32_t r4 = use ? d[4] : (uint32_t)t[4];
  uint32_t r6 = use ? d[6] : (uint32_t)t[6];

  // Output int32 = low 32 bits of each 64-bit word = even 32-bit limbs.
  out[idx] = make_int4((int)r0, (int)r2, (int)r4, (int)r6);
}

extern "C" void kernel_launch(void* const* d_in, const int* in_sizes, int n_in,
                              void* d_out, int out_size, void* d_ws, size_t ws_size,
                              hipStream_t stream) {
  const int4* in1 = (const int4*)d_in[0];
  const int4* in2 = (const int4*)d_in[1];
  int4* out = (int4*)d_out;
  int n = in_sizes[0] / 4;  // (N,4) -> N elements

  const int block = 256;
  const int grid = (n + block - 1) / block;
  fr_tomont_add_kernel<<<grid, block, 0, stream>>>(in1, in2, out, n);
}